// Round 7
// baseline (12409.339 us; speedup 1.0000x reference)
//
#include <hip/hip_runtime.h>
#include <hip/hip_bf16.h>
#include <cstdint>

// ---------------------------------------------------------------------------
// BiLSTM layer, persistent kernel (round 7: factory/consumer pipeline split).
//   B=64, S=512, I=H=1024.  out = [fwd(B,S,H) | bwd(B,S,H)] fp32.
// 256 blocks x 512 threads, 1 block/CU.
//   dir  = bid&1
//   role = (bid>>3)&1     : 0 = recurrence (rec), 1 = xg factory
//   idx  = (bid>>4)*4 + ((bid>>1)&3)  in [0,64): hidden slice n0=idx*16
// FACTORY idx (128 blocks): computes xg[t][b][n-slice][4 gates] = x_t@Wih^T
//   + b_ih + b_hh, fp16, into a 16-slot global ring, steps AHEAD of the
//   recurrence. Paired 1:1 with rec idx (single-flag handshake each way).
// REC idx (128 blocks): per step: poll(64 h-flags + 1 xg-flag) -> h DMA
//   (SC0|SC1 bypass, proven r5 semantics) -> hh GEMM (K=1024, 64 gate cols)
//   -> gates = xg + hh -> h agent-store -> release. NO x panel, NO x GEMM:
//   the x leg (128KiB stage + GEMM + vmcnt entanglement) leaves the serial
//   chain entirely -- the hypothesis this round tests.
// Weights stay VGPR-resident in both roles (Whh for rec, Wih for factory).
// ws: flags 1KiB @0, h-ring 512KiB @4096, xg ring 16MiB @1MiB (~18 MiB).
// ---------------------------------------------------------------------------

typedef __bf16 bf16_t;
typedef bf16_t bf16x8 __attribute__((ext_vector_type(8)));
typedef float  f32x4  __attribute__((ext_vector_type(4)));
typedef uint32_t u32x4 __attribute__((ext_vector_type(4)));

#define DEVI __device__ __forceinline__

constexpr int Bb = 64, Ss = 512, Ii = 1024, Hh = 1024;
constexpr int RING = 16;                       // xg ring depth (steps)
constexpr size_t WS_FLAGS = 0;                 // 256 ints: rflags[128], pflags[128]
constexpr size_t WS_HRING = 4096;              // 2dir*2slot*64*1024 bf16 = 512 KiB
constexpr size_t WS_XG    = 1ull << 20;        // RING*2*64*1024*4 fp16 = 16 MiB
constexpr int LDS_TOTAL = 163840;              // panel 128K | part 32K

DEVI float fast_sig(float x) {
  float z = __expf(-fabsf(x));
  float r = __builtin_amdgcn_rcpf(1.f + z);
  return x >= 0.f ? r : z * r;
}
DEVI float fast_tanh(float x) {
  float z = __expf(-2.f * fabsf(x));
  float r = (1.f - z) * __builtin_amdgcn_rcpf(1.f + z);
  return x >= 0.f ? r : -r;
}
DEVI bf16x8 cvt8(f32x4 a, f32x4 b) {
  bf16x8 r;
  r[0] = (bf16_t)a[0]; r[1] = (bf16_t)a[1]; r[2] = (bf16_t)a[2]; r[3] = (bf16_t)a[3];
  r[4] = (bf16_t)b[0]; r[5] = (bf16_t)b[1]; r[6] = (bf16_t)b[2]; r[7] = (bf16_t)b[3];
  return r;
}
DEVI f32x4 mfma16(bf16x8 a, bf16x8 b, f32x4 c) {
  return __builtin_amdgcn_mfma_f32_16x16x32_bf16(a, b, c, 0, 0, 0);
}
DEVI float f16f(uint16_t h) { union { uint16_t u; _Float16 f; } c; c.u = h; return (float)c.f; }
DEVI uint16_t ff16(float x) { union { uint16_t u; _Float16 f; } c; c.f = (_Float16)x; return c.u; }

// aux CPol: SC0=1, SC1=16. 17 = bypass L1/L2, read at MALL (device-coherent).
#define GLDS16_COH(g, s)                                                       \
  __builtin_amdgcn_global_load_lds(                                            \
      (const __attribute__((address_space(1))) void*)(const void*)(g),         \
      (__attribute__((address_space(3))) void*)(void*)(s), 16, 0, 17)
#define WAIT_LGKM0 asm volatile("s_waitcnt lgkmcnt(0)" ::: "memory")
#define WAIT_VM0   asm volatile("s_waitcnt vmcnt(0)" ::: "memory")
#define BARRIER_RAW                                                            \
  do { __builtin_amdgcn_s_barrier(); __builtin_amdgcn_sched_barrier(0); } while (0)

DEVI int flag_ld(const int* p) {
  return __hip_atomic_load(p, __ATOMIC_RELAXED, __HIP_MEMORY_SCOPE_AGENT);
}
DEVI void flag_st(int* p, int v) {
  __hip_atomic_store(p, v, __ATOMIC_RELAXED, __HIP_MEMORY_SCOPE_AGENT);
}

__global__ void k_init(int* flags) {
  if (threadIdx.x < 256) flags[threadIdx.x] = 0;
}

__global__ void __launch_bounds__(512, 2)
k_lstm(const float* __restrict__ xf, const float* __restrict__ xb,
       const float* __restrict__ Wih_f, const float* __restrict__ Whh_f,
       const float* __restrict__ bih_f, const float* __restrict__ bhh_f,
       const float* __restrict__ Wih_b, const float* __restrict__ Whh_b,
       const float* __restrict__ bih_b, const float* __restrict__ bhh_b,
       float* __restrict__ out,
       uint16_t* __restrict__ xg, bf16_t* __restrict__ hring,
       int* __restrict__ flags) {
  extern __shared__ char lds[];
  char* panel = lds;                       // [64 rows][1024 k] bf16 = 128 KiB
  float* part = (float*)(lds + 131072);    // [2 kq][64 b][64 c] f32 = 32 KiB

  const int tid = threadIdx.x, bid = blockIdx.x;
  const int dir  = bid & 1;
  const int role = (bid >> 3) & 1;
  const int idx  = ((bid >> 4) << 2) | ((bid >> 1) & 3);   // [0,64)
  const int n0   = idx * 16;
  const int w = tid >> 6, l = tid & 63, u = l >> 4, l15 = l & 15;
  const int kq = w & 1, mq = (w >> 1) & 1, nq = (w >> 2) & 1;

  const float* x32 = dir ? xb : xf;
  const float* Wih = dir ? Wih_b : Wih_f;
  const float* Whh = dir ? Whh_b : Whh_f;
  const float* bih = dir ? bih_b : bih_f;
  const float* bhh = dir ? bhh_b : bhh_f;
  bf16_t* hr = hring + (size_t)dir * 2 * Bb * Hh;   // [slot][b][h]
  float* outD = out + (size_t)dir * Bb * Ss * Hh;
  int* rflags = flags;                               // [2][64]
  int* pflags = flags + 128;                         // [2][64]

  // ---- weights -> VGPRs (rec: Whh, factory: Wih). 32 frags = 128 VGPR ----
  const float* WM = role ? Wih : Whh;
  bf16x8 wr[16][2];
#pragma unroll
  for (int ks = 0; ks < 16; ++ks)
#pragma unroll
    for (int nt = 0; nt < 2; ++nt) {
      int c = nq * 32 + nt * 16 + l15;                 // gate col in [0,64)
      int j = (c >> 4) * 1024 + n0 + (c & 15);         // W row (gate-major)
      int k = kq * 512 + ks * 32 + u * 8;
      const float* sp = WM + (size_t)j * 1024 + k;
      wr[ks][nt] = cvt8(*(const f32x4*)sp, *(const f32x4*)(sp + 4));
    }

  // pair map for epilogue phases: thread -> (b=pb, nn0=pn, nn1=pn+1)
  const int pb = tid >> 3;
  const int pn = (tid & 7) * 2;

  // A-fragment geometry (panel [64][1024]bf16, granule(16B) swizzle s^(row&7))
  const int row0 = mq * 32 + l15, row1 = row0 + 16;
  const int ab0 = row0 * 2048, ab1 = row1 * 2048;
  const int x0 = row0 & 7, x1 = row1 & 7;
  const int sbase = kq * 64 + u;

#define COMPUTE                                                                \
  _Pragma("unroll") for (int ks = 0; ks < 16; ++ks) {                          \
    int s_ = sbase + ks * 4;                                                   \
    bf16x8 a0_ = *(const bf16x8*)(panel + ab0 + ((s_ ^ x0) << 4));             \
    bf16x8 a1_ = *(const bf16x8*)(panel + ab1 + ((s_ ^ x1) << 4));             \
    acc00 = mfma16(a0_, wr[ks][0], acc00);                                     \
    acc01 = mfma16(a0_, wr[ks][1], acc01);                                     \
    acc10 = mfma16(a1_, wr[ks][0], acc10);                                     \
    acc11 = mfma16(a1_, wr[ks][1], acc11);                                     \
  }

#define PW(A, RR, NT)                                                          \
  _Pragma("unroll") for (int q = 0; q < 4; ++q) {                              \
    int R = mq * 32 + RR * 16 + u * 4 + q;                                     \
    int C = nq * 32 + NT * 16 + l15;                                           \
    part[((kq << 6) + R) * 64 + (C ^ ((R & 7) << 3))] = A[q];                  \
  }

  if (role == 1) {
    // ================= FACTORY: xg[t] = x_t @ Wih^T + bias, ahead ==========
    float bias_[2][4];
#pragma unroll
    for (int p = 0; p < 2; ++p)
#pragma unroll
      for (int g = 0; g < 4; ++g) {
        int jj = g * 1024 + n0 + pn + p;
        bias_[p][g] = bih[jj] + bhh[jj];
      }

    for (int step = 0; step < Ss; ++step) {
      const int tt = dir ? (Ss - 1 - step) : step;
      // F1: stage x_t panel via registers (fp32 -> bf16), swizzled layout
#pragma unroll
      for (int i = 0; i < 8; ++i) {
        int row = w * 8 + i;
        const float* rp = x32 + ((size_t)row * Ss + tt) * Ii;
#pragma unroll
        for (int h2 = 0; h2 < 2; ++h2) {
          int g16 = h2 * 64 + l;
          int sg = g16 ^ (row & 7);
          f32x4 a = *(const f32x4*)(rp + sg * 8);
          f32x4 b = *(const f32x4*)(rp + sg * 8 + 4);
          *(bf16x8*)(panel + row * 2048 + g16 * 16) = cvt8(a, b);
        }
      }
      WAIT_LGKM0; BARRIER_RAW;
      // F2: GEMM
      f32x4 acc00{0,0,0,0}, acc01 = acc00, acc10 = acc00, acc11 = acc00;
      COMPUTE;
      WAIT_LGKM0;
      PW(acc00, 0, 0) PW(acc01, 0, 1) PW(acc10, 1, 0) PW(acc11, 1, 1)
      WAIT_LGKM0; BARRIER_RAW;
      // F3: ring credit (partner rec must have consumed slot's old step)
      if (step >= RING && tid == 0) {
        const int* cf = &rflags[dir * 64 + idx];
        while (flag_ld(cf) < step - RING + 1) {}
      }
      BARRIER_RAW;
      // F4: epilogue: sum K-halves + bias, fp16-pack, agent-store to ring
      uint16_t* slotp = xg + (((size_t)(step & (RING - 1)) * 2 + dir) << 18);
#pragma unroll
      for (int p = 0; p < 2; ++p) {
        int nn = pn + p;
        uint64_t q8 = 0;
#pragma unroll
        for (int g = 0; g < 4; ++g) {
          int cs = (g * 16 + nn) ^ ((pb & 7) << 3);
          float v = part[pb * 64 + cs] + part[(64 + pb) * 64 + cs] + bias_[p][g];
          q8 |= (uint64_t)ff16(v) << (16 * g);
        }
        unsigned long long* dst =
            (unsigned long long*)(slotp + (size_t)pb * 4096 + (size_t)(n0 + nn) * 4);
        __hip_atomic_store(dst, q8, __ATOMIC_RELAXED, __HIP_MEMORY_SCOPE_AGENT);
      }
      WAIT_VM0; BARRIER_RAW;
      if (tid == 0) flag_st(&pflags[dir * 64 + idx], step + 1);
    }
  } else {
    // ================= REC: the serial recurrence chain ====================
    float c0 = 0.f, c1 = 0.f;
    for (int step = 0; step < Ss; ++step) {
      const int tt = dir ? (Ss - 1 - step) : step;
      // R1: poll h producers (64 flags) + partner factory (1 flag)
      if (step > 0 && tid < 64) {
        const int* fp = &rflags[dir * 64 + tid];
        while (flag_ld(fp) < step) {}
      }
      if (tid == 64) {
        const int* fp = &pflags[dir * 64 + idx];
        while (flag_ld(fp) < step + 1) {}
      }
      BARRIER_RAW;
      // R2: issue xg load (16B/thread, bypass) + h panel DMA (bypass)
      const uint16_t* xaddr = xg + (((size_t)(step & (RING - 1)) * 2 + dir) << 18)
                                 + (size_t)pb * 4096 + (size_t)(n0 + pn) * 4;
      u32x4 xv;
      asm volatile("global_load_dwordx4 %0, %1, off sc0 sc1"
                   : "=v"(xv) : "v"((uint64_t)xaddr) : "memory");
      if (step > 0) {
        const bf16_t* hb = hr + (size_t)((step - 1) & 1) * (Bb * Hh);
#pragma unroll
        for (int i = 0; i < 8; ++i) {
          int row = w * 8 + i;
#pragma unroll
          for (int h2 = 0; h2 < 2; ++h2) {
            const bf16_t* gp = hb + (size_t)row * 1024 + (((h2 * 64 + l) ^ (row & 7)) << 3);
            GLDS16_COH(gp, panel + row * 2048 + h2 * 1024);
          }
        }
      }
      WAIT_VM0; BARRIER_RAW;
      // R3: hh GEMM + K-partials
      f32x4 acc00{0,0,0,0}, acc01 = acc00, acc10 = acc00, acc11 = acc00;
      if (step > 0) {
        COMPUTE;
        WAIT_LGKM0;
        PW(acc00, 0, 0) PW(acc01, 0, 1) PW(acc10, 1, 0) PW(acc11, 1, 1)
        WAIT_LGKM0;
      }
      BARRIER_RAW;
      // R4: gates = xg (+ hh partials), state update, stores
      {
        union { u32x4 v; uint32_t uu[4]; } xu; xu.v = xv;
        float hh0, hh1;
        float houts[2];
#pragma unroll
        for (int p = 0; p < 2; ++p) {
          int nn = pn + p;
          float g0 = f16f((uint16_t)(xu.uu[2 * p] & 0xffff));
          float g1 = f16f((uint16_t)(xu.uu[2 * p] >> 16));
          float g2 = f16f((uint16_t)(xu.uu[2 * p + 1] & 0xffff));
          float g3 = f16f((uint16_t)(xu.uu[2 * p + 1] >> 16));
          if (step > 0) {
            int sk = (pb & 7) << 3;
            g0 += part[pb * 64 + ((0 * 16 + nn) ^ sk)] + part[(64 + pb) * 64 + ((0 * 16 + nn) ^ sk)];
            g1 += part[pb * 64 + ((1 * 16 + nn) ^ sk)] + part[(64 + pb) * 64 + ((1 * 16 + nn) ^ sk)];
            g2 += part[pb * 64 + ((2 * 16 + nn) ^ sk)] + part[(64 + pb) * 64 + ((2 * 16 + nn) ^ sk)];
            g3 += part[pb * 64 + ((3 * 16 + nn) ^ sk)] + part[(64 + pb) * 64 + ((3 * 16 + nn) ^ sk)];
          }
          float ig = fast_sig(g0), fg = fast_sig(g1);
          float gg = fast_tanh(g2), og = fast_sig(g3);
          float& cc = p ? c1 : c0;
          cc = fg * cc + ig * gg;
          houts[p] = og * fast_tanh(cc);
        }
        hh0 = houts[0]; hh1 = houts[1];
        // fp32 output
        float2 o2; o2.x = hh0; o2.y = hh1;
        *(float2*)(outD + (size_t)pb * (Ss * Hh) + (size_t)tt * Hh + n0 + pn) = o2;
        // bf16 h to ring: packed u32 agent store (write-through to MALL)
        union { bf16_t b[2]; uint32_t u; } pk;
        pk.b[0] = (bf16_t)hh0; pk.b[1] = (bf16_t)hh1;
        uint32_t* hdst = (uint32_t*)&hr[(size_t)(step & 1) * (Bb * Hh) +
                                        (size_t)pb * Hh + n0 + pn];
        __hip_atomic_store(hdst, pk.u, __ATOMIC_RELAXED, __HIP_MEMORY_SCOPE_AGENT);
      }
      // R5: drain stores, release
      WAIT_VM0; BARRIER_RAW;
      if (tid == 0) flag_st(&rflags[dir * 64 + idx], step + 1);
    }
  }
#undef COMPUTE
#undef PW
}

extern "C" void kernel_launch(void* const* d_in, const int* in_sizes, int n_in,
                              void* d_out, int out_size, void* d_ws, size_t ws_size,
                              hipStream_t stream) {
  (void)in_sizes; (void)n_in; (void)out_size; (void)ws_size;
  const float* xf    = (const float*)d_in[0];
  const float* xb    = (const float*)d_in[1];
  const float* Wih_f = (const float*)d_in[2];
  const float* Whh_f = (const float*)d_in[3];
  const float* bih_f = (const float*)d_in[4];
  const float* bhh_f = (const float*)d_in[5];
  const float* Wih_b = (const float*)d_in[6];
  const float* Whh_b = (const float*)d_in[7];
  const float* bih_b = (const float*)d_in[8];
  const float* bhh_b = (const float*)d_in[9];
  float* outp = (float*)d_out;
  char* ws = (char*)d_ws;
  int* flagsp = (int*)(ws + WS_FLAGS);
  bf16_t* hringp = (bf16_t*)(ws + WS_HRING);
  uint16_t* xgp = (uint16_t*)(ws + WS_XG);

  hipLaunchKernelGGL(k_init, dim3(1), dim3(256), 0, stream, flagsp);

  void* args[] = {&xf, &xb, &Wih_f, &Whh_f, &bih_f, &bhh_f,
                  &Wih_b, &Whh_b, &bih_b, &bhh_b,
                  &outp, &xgp, &hringp, &flagsp};
  void (*kp)(const float*, const float*, const float*, const float*,
             const float*, const float*, const float*, const float*,
             const float*, const float*, float*, uint16_t*, bf16_t*, int*) = k_lstm;
  hipFuncSetAttribute((const void*)kp, hipFuncAttributeMaxDynamicSharedMemorySize,
                      LDS_TOTAL);
  hipLaunchCooperativeKernel((const void*)kp, dim3(256), dim3(512), args,
                             LDS_TOTAL, stream);
}

// Round 9
// 3399.028 us; speedup vs baseline: 3.6508x; 3.6508x over previous
//
#include <hip/hip_runtime.h>
#include <hip/hip_bf16.h>
#include <cstdint>

// ---------------------------------------------------------------------------
// BiLSTM layer, persistent kernel (round 9 = round 8 + 2 correctness fixes).
//   B=64, S=512, I=H=1024.  out = [fwd(B,S,H) | bwd(B,S,H)] fp32.
// 256 blocks x 512 threads, 1 block/CU. dir=bid&1, db=bid>>1, n0=db*8.
// Weights (W_ih|W_hh, K=2048) VGPR-resident as MFMA B-fragments (r2-proven).
//
// h distribution: producers agent-store h to MALL ring (proven r2-r5).
// Per (physical XCD, dir) group -- runtime s_getreg(HW_REG_XCC_ID) + atomic
// election -- members relay ~64/G rows each: bypass-read (sc0 sc1) from MALL
// ONCE PER XCD, plain-store into per-XCD xcdbuf (dirty local L2). Consumers
// DMA the panel from xcdbuf with SC0 loads (L1-bypass, L2-HIT). Cuts h
// fabric traffic 32x vs r3/r5 (every CU bypass-reading the panel from MALL).
//
// ROUND-9 FIXES (r8 shipped garbage -> NaN):
//  (1) relay load: s_waitcnt vmcnt(0) INSIDE the asm -- the compiler does
//      not track inline-asm VMEM latency; r8 stored the dest reg before the
//      load returned (rule-18 family bug).
//  (2) election LDS broadcast: explicit lgkmcnt(0) drain before s_barrier.
// ---------------------------------------------------------------------------

typedef __bf16 bf16_t;
typedef bf16_t bf16x8 __attribute__((ext_vector_type(8)));
typedef float  f32x4  __attribute__((ext_vector_type(4)));

#define DEVI __device__ __forceinline__

constexpr int Bb = 64, Ss = 512, Ii = 1024, Hh = 1024;
constexpr size_t WS_RFLAGS = 0;            // 256 ints  [dir][128]
constexpr size_t WS_ELECT  = 2048;         // 17 ints: 16 group ctrs + total
constexpr size_t WS_XFLAG  = 4096;         // [8 xcd][2 dir][64 rank] ints
constexpr size_t WS_HRING  = 8192;         // 2dir*2par*64*1024 bf16 = 512 KiB
constexpr size_t WS_XCD    = 1ull << 20;   // [8][2][2 par] * 128 KiB = 4 MiB
constexpr size_t WS_XBF    = 16ull << 20;  // x bf16 t-major, 128 MiB
constexpr size_t XBF_BYTES = 2ull * Ss * Bb * Ii * 2;
constexpr size_t NEED_XBF  = WS_XBF + XBF_BYTES;   // 144 MiB
constexpr int LDS_TOTAL = 163840;          // PA 64K | PB 64K | part 32K

DEVI float fast_sig(float x) {
  float z = __expf(-fabsf(x));
  float r = __builtin_amdgcn_rcpf(1.f + z);
  return x >= 0.f ? r : z * r;
}
DEVI float fast_tanh(float x) {
  float z = __expf(-2.f * fabsf(x));
  float r = (1.f - z) * __builtin_amdgcn_rcpf(1.f + z);
  return x >= 0.f ? r : -r;
}
DEVI bf16x8 cvt8(f32x4 a, f32x4 b) {
  bf16x8 r;
  r[0] = (bf16_t)a[0]; r[1] = (bf16_t)a[1]; r[2] = (bf16_t)a[2]; r[3] = (bf16_t)a[3];
  r[4] = (bf16_t)b[0]; r[5] = (bf16_t)b[1]; r[6] = (bf16_t)b[2]; r[7] = (bf16_t)b[3];
  return r;
}
DEVI uint32_t pk_bf16(float lo, float hi) {
  union { bf16_t b[2]; uint32_t u; } x;
  x.b[0] = (bf16_t)lo; x.b[1] = (bf16_t)hi;
  return x.u;
}
DEVI f32x4 mfma16(bf16x8 a, bf16x8 b, f32x4 c) {
  return __builtin_amdgcn_mfma_f32_16x16x32_bf16(a, b, c, 0, 0, 0);
}

// GLDS aux (CPol): 0 = cached; 1 = SC0 (L1-bypass, L2-hit)
#define GLDS16(g, s)                                                           \
  __builtin_amdgcn_global_load_lds(                                            \
      (const __attribute__((address_space(1))) void*)(const void*)(g),         \
      (__attribute__((address_space(3))) void*)(void*)(s), 16, 0, 0)
#define GLDS16_SC0(g, s)                                                       \
  __builtin_amdgcn_global_load_lds(                                            \
      (const __attribute__((address_space(1))) void*)(const void*)(g),         \
      (__attribute__((address_space(3))) void*)(void*)(s), 16, 0, 1)
#define WAIT_LGKM0 asm volatile("s_waitcnt lgkmcnt(0)" ::: "memory")
#define WAIT_VM0   asm volatile("s_waitcnt vmcnt(0)" ::: "memory")
#define BARRIER_RAW                                                            \
  do { __builtin_amdgcn_s_barrier(); __builtin_amdgcn_sched_barrier(0); } while (0)

DEVI int aload(const int* p) {
  return __hip_atomic_load(p, __ATOMIC_RELAXED, __HIP_MEMORY_SCOPE_AGENT);
}
DEVI void astore(int* p, int v) {
  __hip_atomic_store(p, v, __ATOMIC_RELAXED, __HIP_MEMORY_SCOPE_AGENT);
}

__global__ void k_init(int* p) {
  int i = blockIdx.x * blockDim.x + threadIdx.x;
  if (i < 2048) p[i] = 0;   // rflags + elect + xflag region (8 KiB)
}

// x fp32 [dir][b][t][i] -> bf16 t-major [dir][t][b][i]
__global__ void k_convx(const float* __restrict__ xf, const float* __restrict__ xb,
                        bf16_t* __restrict__ dst) {
  size_t og = (size_t)blockIdx.x * blockDim.x + threadIdx.x;
  int i8  = (int)(og & 127);
  int b   = (int)((og >> 7) & 63);
  int t   = (int)((og >> 13) & 511);
  int dir = (int)(og >> 22);
  const float* src = (dir ? xb : xf) + (((size_t)b * Ss + t) * Ii + (size_t)i8 * 8);
  f32x4 a = *(const f32x4*)src;
  f32x4 c = *(const f32x4*)(src + 4);
  *(bf16x8*)(dst + og * 8) = cvt8(a, c);
}

template <bool XBF>
__global__ void __launch_bounds__(512, 2)
k_lstm(const float* __restrict__ xf, const float* __restrict__ xb,
       const float* __restrict__ Wih_f, const float* __restrict__ Whh_f,
       const float* __restrict__ bih_f, const float* __restrict__ bhh_f,
       const float* __restrict__ Wih_b, const float* __restrict__ Whh_b,
       const float* __restrict__ bih_b, const float* __restrict__ bhh_b,
       float* __restrict__ out,
       const bf16_t* __restrict__ xbfin, char* __restrict__ wsb) {
  extern __shared__ char lds[];
  char* PA = lds;                 // half-panel [64 rows][512 k] bf16 = 64 KiB
  char* PB = lds + 65536;
  float* part = (float*)(lds + 131072);   // 32 KiB (also election scratch)

  int*    rflags = (int*)(wsb + WS_RFLAGS);
  int*    elect  = (int*)(wsb + WS_ELECT);
  int*    xflag  = (int*)(wsb + WS_XFLAG);
  bf16_t* hring  = (bf16_t*)(wsb + WS_HRING);
  bf16_t* xcdbuf = (bf16_t*)(wsb + WS_XCD);

  const int tid = threadIdx.x;
  const int bid = blockIdx.x;
  const int dir = bid & 1;
  const int db  = bid >> 1;
  const int n0  = db * 8;
  const int w   = tid >> 6, l = tid & 63;
  const int u   = l >> 4, l15 = l & 15;
  const int m   = w & 1;
  const int kq  = w >> 1;

  const float* Wih = dir ? Wih_b : Wih_f;
  const float* Whh = dir ? Whh_b : Whh_f;
  const float* bih = dir ? bih_b : bih_f;
  const float* bhh = dir ? bhh_b : bhh_f;
  const float* x32 = dir ? xb : xf;
  const bf16_t* xbase = xbfin + (size_t)dir * Ss * Bb * Ii;
  bf16_t* hr = hring + (size_t)dir * 2 * Bb * Hh;
  float* outD = out + (size_t)dir * Bb * Ss * Hh;
  int* myrflags = rflags + dir * 128;

  // ---- one-time: W into VGPRs as B-fragments (r2-proven layout) -----------
  bf16x8 wr[2][2][4][2];
#pragma unroll
  for (int mat = 0; mat < 2; ++mat)
#pragma unroll
    for (int p = 0; p < 2; ++p)
#pragma unroll
      for (int ks = 0; ks < 4; ++ks)
#pragma unroll
        for (int nt = 0; nt < 2; ++nt) {
          int c = nt * 16 + l15;
          int j = (c >> 3) * 1024 + n0 + (c & 7);
          int k = p * 512 + kq * 128 + ks * 32 + u * 8;
          const float* sp = (mat ? Whh : Wih) + (size_t)j * 1024 + k;
          wr[mat][p][ks][nt] = cvt8(*(const f32x4*)sp, *(const f32x4*)(sp + 4));
        }

  const int eb = tid >> 3, en = tid & 7;
  const int nj = n0 + en;
  float bi0 = bih[nj] + bhh[nj];
  float bi1 = bih[1024 + nj] + bhh[1024 + nj];
  float bi2 = bih[2048 + nj] + bhh[2048 + nj];
  float bi3 = bih[3072 + nj] + bhh[3072 + nj];

  int aoff0[4], aoff1[4];
#pragma unroll
  for (int ks = 0; ks < 4; ++ks) {
    int r0_ = m * 32 + l15;
    int r1_ = r0_ + 16;
    int sl = kq * 16 + ks * 4 + u;
    aoff0[ks] = r0_ * 1024 + ((sl ^ (r0_ & 7)) << 4);
    aoff1[ks] = r1_ * 1024 + ((sl ^ (r1_ & 7)) << 4);
  }

  auto STAGE_DMA = [&](char* panel, const bf16_t* srcb) {
#pragma unroll
    for (int i = 0; i < 8; ++i) {
      const bf16_t* gp = srcb + (size_t)(w * 8 + i) * 1024 + ((l ^ i) << 3);
      GLDS16(gp, panel + (w * 8 + i) * 1024);
    }
  };
  auto STAGE_HC = [&](char* panel, const bf16_t* srcb) {   // L2-hit reads
#pragma unroll
    for (int i = 0; i < 8; ++i) {
      const bf16_t* gp = srcb + (size_t)(w * 8 + i) * 1024 + ((l ^ i) << 3);
      GLDS16_SC0(gp, panel + (w * 8 + i) * 1024);
    }
  };
  auto STAGE_XF = [&](char* panel, const float* srcb) {
#pragma unroll
    for (int i = 0; i < 8; ++i) {
      int r = w * 8 + i;
      const float* sp = srcb + (size_t)r * (Ss * Ii) + ((l ^ i) << 3);
      f32x4 a = *(const f32x4*)sp;
      f32x4 b = *(const f32x4*)(sp + 4);
      *(bf16x8*)(panel + r * 1024 + l * 16) = cvt8(a, b);
    }
  };

  // ---- runtime XCD group election (no bid->XCD assumptions) ---------------
  int xcdid;
  asm("s_getreg_b32 %0, hwreg(20, 0, 4)" : "=s"(xcdid));   // HW_REG_XCC_ID
  xcdid &= 7;
  {
    int* bc = (int*)part;
    if (tid == 0) {
      int g = xcdid * 2 + dir;
      int rk = __hip_atomic_fetch_add(&elect[g], 1, __ATOMIC_RELAXED,
                                      __HIP_MEMORY_SCOPE_AGENT);
      __hip_atomic_fetch_add(&elect[16], 1, __ATOMIC_RELAXED,
                             __HIP_MEMORY_SCOPE_AGENT);
      while (aload(&elect[16]) < (int)gridDim.x) {}
      bc[0] = rk;
      bc[1] = aload(&elect[xcdid * 2 + dir]);
    }
    WAIT_LGKM0; BARRIER_RAW;   // FIX(2): drain ds_write before barrier
  }
  const int rank = ((int*)part)[0];
  const int Gn   = ((int*)part)[1];
  BARRIER_RAW;
  const int rowsPer = (64 + Gn - 1) / Gn;
  const int rr0 = rank * rowsPer;
  const int rr1 = (rr0 + rowsPer < 64) ? (rr0 + rowsPer) : 64;
  const int nflag = (64 + rowsPer - 1) / rowsPer;
  int* myxflag = xflag + (xcdid * 2 + dir) * 64;
  bf16_t* xslotbase = xcdbuf + (size_t)((xcdid * 2 + dir) * 2) * 65536;

  f32x4 acc00, acc01, acc10, acc11;
#define COMPUTE(panel, matC, pC)                                               \
  do {                                                                         \
    _Pragma("unroll") for (int ks = 0; ks < 4; ++ks) {                         \
      bf16x8 a0_ = *(const bf16x8*)((panel) + aoff0[ks]);                      \
      bf16x8 a1_ = *(const bf16x8*)((panel) + aoff1[ks]);                      \
      acc00 = mfma16(a0_, wr[matC][pC][ks][0], acc00);                         \
      acc01 = mfma16(a0_, wr[matC][pC][ks][1], acc01);                         \
      acc10 = mfma16(a1_, wr[matC][pC][ks][0], acc10);                         \
      acc11 = mfma16(a1_, wr[matC][pC][ks][1], acc11);                         \
    }                                                                          \
  } while (0)

  float c_reg = 0.f;

  // prologue: stage both X half-panels of the first timestep
  {
    int t0 = dir ? (Ss - 1) : 0;
    if constexpr (XBF) {
      STAGE_DMA(PA, xbase + (size_t)t0 * (Bb * Ii));
      STAGE_DMA(PB, xbase + (size_t)t0 * (Bb * Ii) + 512);
    } else {
      STAGE_XF(PA, x32 + (size_t)t0 * Ii);
      STAGE_XF(PB, x32 + (size_t)t0 * Ii + 512);
    }
  }

  for (int step = 0; step < Ss; ++step) {
    const int t  = dir ? (Ss - 1 - step) : step;
    const int tn = dir ? (Ss - 2 - step) : (step + 1);
    bf16_t* xslot = xslotbase + (size_t)(step & 1) * 65536;

    // P1: poll producers (h_{step-1} at MALL). x prefetch still in flight.
    if (step > 0 && tid < 128) {
      const int* fp = &myrflags[tid];
      while (aload(fp) < step) {}
    }
    BARRIER_RAW;

    // P2: relay my rows of the h panel: MALL bypass -> regs -> local-L2 buf.
    // FIX(1): vmcnt(0) inside the asm -- the register is NOT valid until the
    // load retires; the compiler cannot know that for inline-asm VMEM.
    if (step > 0) {
      const bf16_t* hsrc = hr + (size_t)((step - 1) & 1) * (Bb * Hh);
      int ng = (rr1 - rr0) * 128;    // 16B granules
      for (int gI = tid; gI < ng; gI += 512) {
        int row = rr0 + (gI >> 7), col = gI & 127;
        const void* sp = hsrc + (size_t)row * 1024 + col * 8;
        f32x4 v;
        asm volatile("global_load_dwordx4 %0, %1, off sc0 sc1\n\t"
                     "s_waitcnt vmcnt(0)"
                     : "=v"(v) : "v"((uint64_t)sp) : "memory");
        *(f32x4*)(xslot + (size_t)row * 1024 + col * 8) = v;  // plain: dirty L2
      }
      WAIT_VM0; WAIT_LGKM0; BARRIER_RAW;  // relay stores done; x panels landed
      if (tid == 0 && rr0 < 64) astore(&myxflag[rank], step);
    } else {
      WAIT_VM0; WAIT_LGKM0; BARRIER_RAW;  // prologue x landed
    }

    // P3: x GEMMs (overlaps other blocks' relay + consumer DMA)
    acc00 = f32x4{0.f, 0.f, 0.f, 0.f}; acc01 = acc00; acc10 = acc00; acc11 = acc00;
    COMPUTE(PA, 0, 0);
    COMPUTE(PB, 0, 1);
    WAIT_LGKM0;

    // P4: wait group relays, then DMA h panel from local L2, hh GEMMs
    if (step > 0) {
      if (tid < nflag) {
        const int* fp = &myxflag[tid];
        while (aload(fp) < step) {}
      }
      BARRIER_RAW;
      STAGE_HC(PA, xslot);
      STAGE_HC(PB, xslot + 512);
      WAIT_VM0; BARRIER_RAW;
      COMPUTE(PA, 1, 0);
      COMPUTE(PB, 1, 1);
      WAIT_LGKM0;
    }

    // P5: K-partials to LDS (XOR-swizzled, r3-proven)
#pragma unroll
    for (int rr = 0; rr < 2; ++rr)
#pragma unroll
      for (int nt = 0; nt < 2; ++nt) {
        f32x4 a = (rr == 0) ? (nt == 0 ? acc00 : acc01) : (nt == 0 ? acc10 : acc11);
#pragma unroll
        for (int q = 0; q < 4; ++q) {
          int R = m * 32 + rr * 16 + u * 4 + q;
          int C = nt * 16 + l15;
          part[(kq * 64 + R) * 32 + (C ^ ((R & 7) << 2))] = a[q];
        }
      }
    WAIT_LGKM0; BARRIER_RAW;

    // P6: gates
    {
      const int sk = (eb & 7) << 2;
      float g0 = bi0, g1 = bi1, g2 = bi2, g3 = bi3;
#pragma unroll
      for (int q = 0; q < 4; ++q) {
        const float* pp = &part[(q * 64 + eb) * 32];
        g0 += pp[en ^ sk]; g1 += pp[(8 + en) ^ sk];
        g2 += pp[(16 + en) ^ sk]; g3 += pp[(24 + en) ^ sk];
      }
      float ig = fast_sig(g0), fg = fast_sig(g1);
      float gg = fast_tanh(g2), og = fast_sig(g3);
      c_reg = fg * c_reg + ig * gg;
      float h = og * fast_tanh(c_reg);
      outD[(size_t)eb * (Ss * Hh) + (size_t)t * Hh + n0 + en] = h;
      uint32_t p01 = pk_bf16(h, __shfl_xor(h, 1));
      uint32_t p23 = __shfl_xor(p01, 2);
      if ((en & 3) == 0) {
        uint64_t q8 = (uint64_t)p01 | ((uint64_t)p23 << 32);
        uint64_t* dst = (uint64_t*)&hr[(size_t)(step & 1) * (Bb * Hh) +
                                       (size_t)eb * Hh + n0 + (en & 4)];
        __hip_atomic_store(dst, q8, __ATOMIC_RELAXED, __HIP_MEMORY_SCOPE_AGENT);
      }
    }

    // P7: drain this step's stores ONLY (prefetch not yet issued), release
    WAIT_VM0; BARRIER_RAW;
    if (tid == 0) astore(&myrflags[db], step + 1);

    // P8: x prefetch for next step (lands during next poll/relay window)
    if (step < Ss - 1) {
      if constexpr (XBF) {
        STAGE_DMA(PA, xbase + (size_t)tn * (Bb * Ii));
        STAGE_DMA(PB, xbase + (size_t)tn * (Bb * Ii) + 512);
      } else {
        STAGE_XF(PA, x32 + (size_t)tn * Ii);
        STAGE_XF(PB, x32 + (size_t)tn * Ii + 512);
      }
    }
  }
#undef COMPUTE
}

extern "C" void kernel_launch(void* const* d_in, const int* in_sizes, int n_in,
                              void* d_out, int out_size, void* d_ws, size_t ws_size,
                              hipStream_t stream) {
  (void)in_sizes; (void)n_in; (void)out_size;
  const float* xf    = (const float*)d_in[0];
  const float* xb    = (const float*)d_in[1];
  const float* Wih_f = (const float*)d_in[2];
  const float* Whh_f = (const float*)d_in[3];
  const float* bih_f = (const float*)d_in[4];
  const float* bhh_f = (const float*)d_in[5];
  const float* Wih_b = (const float*)d_in[6];
  const float* Whh_b = (const float*)d_in[7];
  const float* bih_b = (const float*)d_in[8];
  const float* bhh_b = (const float*)d_in[9];
  float* outp = (float*)d_out;
  char* ws = (char*)d_ws;

  const bool xbf = ws_size >= NEED_XBF + (1u << 20);
  bf16_t* xbfp = (bf16_t*)(ws + WS_XBF);

  hipLaunchKernelGGL(k_init, dim3(2), dim3(1024), 0, stream, (int*)ws);
  if (xbf) {
    hipLaunchKernelGGL(k_convx, dim3(32768), dim3(256), 0, stream, xf, xb, xbfp);
  }

  const bf16_t* xbfc = xbfp;
  void* args[] = {&xf, &xb, &Wih_f, &Whh_f, &bih_f, &bhh_f,
                  &Wih_b, &Whh_b, &bih_b, &bhh_b,
                  &outp, &xbfc, &ws};
  using KFn = void (*)(const float*, const float*, const float*, const float*,
                       const float*, const float*, const float*, const float*,
                       const float*, const float*, float*, const bf16_t*, char*);
  KFn kp = xbf ? (KFn)k_lstm<true> : (KFn)k_lstm<false>;
  hipFuncSetAttribute((const void*)kp, hipFuncAttributeMaxDynamicSharedMemorySize,
                      LDS_TOTAL);
  hipLaunchCooperativeKernel((const void*)kp, dim3(256), dim3(512), args,
                             LDS_TOTAL, stream);
}